// Round 1
// baseline (363.877 us; speedup 1.0000x reference)
//
#include <hip/hip_runtime.h>

// Per-channel 8x8 box sum, stride 4, VALID padding.
// Input  x: (8, 32, 512, 512) fp32  (NCHW)
// Output  : (8, 32, 127, 127) fp32
//
// Strategy: one thread per (nc, ow, oh-chunk-of-16). Columns ow*4..ow*4+7
// are 16B aligned -> two float4 loads per input row, coalesced across the
// 64 ow-lanes of a wave. Vertical separability: rolling sum of 4 row-sums
// (windows at stride 4 with k=8 share exactly 4 rows), so each input row
// is loaded/summed once per thread.

#define NB 8
#define CB 32
#define HH 512
#define WW 512
#define OH 127
#define OW 127
#define CHUNK 16   // output rows per thread

__global__ __launch_bounds__(256) void boxsum8x8s4_kernel(
    const float* __restrict__ x, float* __restrict__ out)
{
    const int ow    = blockIdx.x * 64 + threadIdx.x;       // 0..127 (127 inactive)
    const int chunk = blockIdx.y * blockDim.y + threadIdx.y; // 0..7
    const int nc    = blockIdx.z;                           // 0..255
    if (ow >= OW) return;

    const int oh0 = chunk * CHUNK;
    const int oh1 = (oh0 + CHUNK < OH) ? (oh0 + CHUNK) : OH;

    const float* base  = x + (size_t)nc * HH * WW + (size_t)ow * 4;
    float*       obase = out + (size_t)nc * OH * OW + ow;

    // horizontal sum of the 8 columns of one input row
    auto rowsum = [&](int row) -> float {
        const float4* p = reinterpret_cast<const float4*>(base + (size_t)row * WW);
        float4 a = p[0];
        float4 b = p[1];
        return (a.x + a.y) + (a.z + a.w) + (b.x + b.y) + (b.z + b.w);
    };

    int r0 = oh0 * 4;
    float prev4 = rowsum(r0) + rowsum(r0 + 1) + rowsum(r0 + 2) + rowsum(r0 + 3);

    for (int oh = oh0; oh < oh1; ++oh) {
        const int r = oh * 4 + 4;
        float cur4 = rowsum(r) + rowsum(r + 1) + rowsum(r + 2) + rowsum(r + 3);
        obase[(size_t)oh * OW] = prev4 + cur4;
        prev4 = cur4;
    }
}

extern "C" void kernel_launch(void* const* d_in, const int* in_sizes, int n_in,
                              void* d_out, int out_size, void* d_ws, size_t ws_size,
                              hipStream_t stream) {
    const float* x = (const float*)d_in[0];
    float* out = (float*)d_out;

    dim3 block(64, 4, 1);          // 4 waves/block
    dim3 grid(2, 2, NB * CB);      // ow: 2*64>=127, oh-chunks: 2*4=8, nc: 256
    boxsum8x8s4_kernel<<<grid, block, 0, stream>>>(x, out);
}